// Round 2
// baseline (167.089 us; speedup 1.0000x reference)
//
#include <hip/hip_runtime.h>

#define BINS 4096            // 64 * 64
#define HIST_BLOCKS 1024
#define HIST_THREADS 512     // 8 waves/block; ~80 VGPR -> 3 blocks/CU = 24 waves
#define PAIRS 8              // int4 pairs per thread: 16 dwordx4 (16 KB) in flight

// out[i] = transitions_in[i] for i < bins; out[bins] = total_in + n_events
__global__ void topo_init_kernel(const float* __restrict__ transitions,
                                 const float* __restrict__ total,
                                 float* __restrict__ out,
                                 float n_events_f, int bins) {
    int i = blockIdx.x * blockDim.x + threadIdx.x;
    if (i < bins) out[i] = transitions[i];
    if (i == 0) out[bins] = total[0] + n_events_f;
}

__global__ void __launch_bounds__(HIST_THREADS)
topo_hist_kernel(const int* __restrict__ prev,
                 const int* __restrict__ curr,
                 float* __restrict__ out, int n) {
    __shared__ unsigned int h[BINS];
    for (int i = threadIdx.x; i < BINS; i += HIST_THREADS) h[i] = 0u;
    __syncthreads();

    const int n4 = n >> 2;
    const int4* __restrict__ p4 = (const int4*)prev;
    const int4* __restrict__ c4 = (const int4*)curr;

    const int chunk  = HIST_THREADS * PAIRS;      // int4s per block per pass
    const int stride = gridDim.x * chunk;
    int i = blockIdx.x * chunk + threadIdx.x;

    // Fast path: 8 int4-pairs per thread per pass. All 16 global_load_dwordx4
    // are issued before any consume (MLP: 16 KB in flight per wave); the LDS
    // atomic bursts then overlap the remaining loads' latency via staged vmcnt.
    // For n=16.7M this grid covers everything in exactly ONE pass (no seam).
    while (i + (PAIRS - 1) * HIST_THREADS < n4) {
        int4 P[PAIRS], C[PAIRS];
#pragma unroll
        for (int k = 0; k < PAIRS; ++k) P[k] = p4[i + k * HIST_THREADS];
#pragma unroll
        for (int k = 0; k < PAIRS; ++k) C[k] = c4[i + k * HIST_THREADS];
#pragma unroll
        for (int k = 0; k < PAIRS; ++k) {
            atomicAdd(&h[(P[k].x << 6) | C[k].x], 1u);
            atomicAdd(&h[(P[k].y << 6) | C[k].y], 1u);
            atomicAdd(&h[(P[k].z << 6) | C[k].z], 1u);
            atomicAdd(&h[(P[k].w << 6) | C[k].w], 1u);
        }
        i += stride;
    }
    // Leftover full int4s for this thread (first failing base only: stride
    // exceeds the guard window, so at most one partial group per thread).
#pragma unroll
    for (int k = 0; k < PAIRS; ++k) {
        int idx = i + k * HIST_THREADS;
        if (idx < n4) {
            int4 p = p4[idx];
            int4 c = c4[idx];
            atomicAdd(&h[(p.x << 6) | c.x], 1u);
            atomicAdd(&h[(p.y << 6) | c.y], 1u);
            atomicAdd(&h[(p.z << 6) | c.z], 1u);
            atomicAdd(&h[(p.w << 6) | c.w], 1u);
        }
    }
    // Scalar tail (n not divisible by 4 — not hit for 16.7M, kept for safety)
    for (int t = (n4 << 2) + blockIdx.x * HIST_THREADS + threadIdx.x; t < n;
         t += gridDim.x * HIST_THREADS) {
        atomicAdd(&h[(prev[t] << 6) | curr[t]], 1u);
    }

    __syncthreads();
    // Round-1 finding: this contended float-atomic flush is FREE (removing it
    // changed hist duration by 0.2%) — keep the simple single-kernel form.
    for (int b = threadIdx.x; b < BINS; b += HIST_THREADS) {
        unsigned int c = h[b];
        if (c) atomicAdd(&out[b], (float)c);
    }
}

extern "C" void kernel_launch(void* const* d_in, const int* in_sizes, int n_in,
                              void* d_out, int out_size, void* d_ws, size_t ws_size,
                              hipStream_t stream) {
    const int*   prev        = (const int*)d_in[0];
    const int*   curr        = (const int*)d_in[1];
    const float* transitions = (const float*)d_in[2];
    const float* total       = (const float*)d_in[3];
    float* out = (float*)d_out;

    const int n    = in_sizes[0];
    const int bins = in_sizes[2];   // 4096

    // 1) initialize output: copy transitions input, set total = total_in + n
    int init_blocks = (bins + 1 + 255) / 256;
    topo_init_kernel<<<init_blocks, 256, 0, stream>>>(transitions, total, out,
                                                      (float)n, bins);

    // 2) per-block LDS histogram + atomic flush (single kernel, max-MLP loop)
    topo_hist_kernel<<<HIST_BLOCKS, HIST_THREADS, 0, stream>>>(prev, curr, out, n);
}

// Round 3
// 166.206 us; speedup vs baseline: 1.0053x; 1.0053x over previous
//
#include <hip/hip_runtime.h>

#define BINS 4096            // 64 * 64
#define HIST_BLOCKS 1024
#define HIST_THREADS 512
#define PAIRS 8              // int4 pairs per thread: 16 dwordx4 = 16 KB in flight

// out[i] = transitions_in[i] for i < bins; out[bins] = total_in + n_events
__global__ void topo_init_kernel(const float* __restrict__ transitions,
                                 const float* __restrict__ total,
                                 float* __restrict__ out,
                                 float n_events_f, int bins) {
    int i = blockIdx.x * blockDim.x + threadIdx.x;
    if (i < bins) out[i] = transitions[i];
    if (i == 0) out[bins] = total[0] + n_events_f;
}

__global__ void __launch_bounds__(HIST_THREADS)
topo_hist_kernel(const int* __restrict__ prev,
                 const int* __restrict__ curr,
                 float* __restrict__ out, int n) {
    __shared__ unsigned int h[BINS];
    for (int i = threadIdx.x; i < BINS; i += HIST_THREADS) h[i] = 0u;
    __syncthreads();

    const int n4 = n >> 2;
    const int4* __restrict__ p4 = (const int4*)prev;
    const int4* __restrict__ c4 = (const int4*)curr;
    const int total_threads = gridDim.x * HIST_THREADS;
    const int tid = blockIdx.x * HIST_THREADS + threadIdx.x;

    if (n4 == total_threads * PAIRS && (n & 3) == 0) {
        // Exact-cover fast path (n = 16.7M): straight-line, no loop seam.
        // Issue ALL 16 loads before ANY consume. The sched_barrier(0) is the
        // critical piece: R0/R2 showed the compiler otherwise rewrites this
        // into a min-register (VGPR=12!) load->wait->consume serialization
        // with ~1 load in flight. The fence forces ~16 KB/wave in flight;
        // the consume loop then gets dependence-staged vmcnt(N) waits.
        const int base = blockIdx.x * (HIST_THREADS * PAIRS) + threadIdx.x;
        int4 P[PAIRS], C[PAIRS];
#pragma unroll
        for (int k = 0; k < PAIRS; ++k) {
            P[k] = p4[base + k * HIST_THREADS];
            C[k] = c4[base + k * HIST_THREADS];
        }
        __builtin_amdgcn_sched_barrier(0);
#pragma unroll
        for (int k = 0; k < PAIRS; ++k) {
            atomicAdd(&h[(P[k].x << 6) | C[k].x], 1u);
            atomicAdd(&h[(P[k].y << 6) | C[k].y], 1u);
            atomicAdd(&h[(P[k].z << 6) | C[k].z], 1u);
            atomicAdd(&h[(P[k].w << 6) | C[k].w], 1u);
        }
    } else {
        // Generic fallback: R0-style grid-stride (correct for any n).
        for (int i = tid; i < n4; i += total_threads) {
            int4 p = p4[i];
            int4 c = c4[i];
            atomicAdd(&h[(p.x << 6) | c.x], 1u);
            atomicAdd(&h[(p.y << 6) | c.y], 1u);
            atomicAdd(&h[(p.z << 6) | c.z], 1u);
            atomicAdd(&h[(p.w << 6) | c.w], 1u);
        }
        for (int t = (n4 << 2) + tid; t < n; t += total_threads) {
            atomicAdd(&h[(prev[t] << 6) | curr[t]], 1u);
        }
    }

    __syncthreads();
    // R1 finding: this contended float-atomic flush is FREE (hist duration
    // identical with/without it) — keep the simple single-kernel form.
    for (int b = threadIdx.x; b < BINS; b += HIST_THREADS) {
        unsigned int c = h[b];
        if (c) atomicAdd(&out[b], (float)c);
    }
}

extern "C" void kernel_launch(void* const* d_in, const int* in_sizes, int n_in,
                              void* d_out, int out_size, void* d_ws, size_t ws_size,
                              hipStream_t stream) {
    const int*   prev        = (const int*)d_in[0];
    const int*   curr        = (const int*)d_in[1];
    const float* transitions = (const float*)d_in[2];
    const float* total       = (const float*)d_in[3];
    float* out = (float*)d_out;

    const int n    = in_sizes[0];
    const int bins = in_sizes[2];   // 4096

    // 1) initialize output: copy transitions input, set total = total_in + n
    int init_blocks = (bins + 1 + 255) / 256;
    topo_init_kernel<<<init_blocks, 256, 0, stream>>>(transitions, total, out,
                                                      (float)n, bins);

    // 2) per-block LDS histogram + atomic flush (forced-MLP straight-line loop)
    topo_hist_kernel<<<HIST_BLOCKS, HIST_THREADS, 0, stream>>>(prev, curr, out, n);
}

// Round 5
// 154.576 us; speedup vs baseline: 1.0809x; 1.0752x over previous
//
#include <hip/hip_runtime.h>

#define BINS 4096            // 64 * 64
#define HIST_BLOCKS 1024
#define HIST_THREADS 512
#define PAIRS 8              // 8 (p,c) int4 pairs per thread = 16 dwordx4 in flight

typedef int intx4 __attribute__((ext_vector_type(4)));

// out[i] = transitions_in[i] for i < bins; out[bins] = total_in + n_events
__global__ void topo_init_kernel(const float* __restrict__ transitions,
                                 const float* __restrict__ total,
                                 float* __restrict__ out,
                                 float n_events_f, int bins) {
    int i = blockIdx.x * blockDim.x + threadIdx.x;
    if (i < bins) out[i] = transitions[i];
    if (i == 0) out[bins] = total[0] + n_events_f;
}

#define CONS(Pk, Ck)                                    \
    atomicAdd(&h[(Pk.x << 6) | Ck.x], 1u);              \
    atomicAdd(&h[(Pk.y << 6) | Ck.y], 1u);              \
    atomicAdd(&h[(Pk.z << 6) | Ck.z], 1u);              \
    atomicAdd(&h[(Pk.w << 6) | Ck.w], 1u)

// Counted-vmcnt wait that also read-write-ties the pair being consumed:
// the "+v" outputs make every consumer data-dependent on the POST-wait asm,
// so the compiler cannot hoist VALU uses above the wait (rule #18 hazard).
#define WAITPAIR(N, Pk, Ck)                             \
    asm volatile("s_waitcnt vmcnt(" #N ")"              \
                 : "+v"(Pk), "+v"(Ck)::"memory")

__global__ void __launch_bounds__(HIST_THREADS)
topo_hist_kernel(const int* __restrict__ prev,
                 const int* __restrict__ curr,
                 float* __restrict__ out, int n) {
    __shared__ unsigned int h[BINS];
    for (int i = threadIdx.x; i < BINS; i += HIST_THREADS) h[i] = 0u;
    __syncthreads();

    const int n4 = n >> 2;
    const int total_threads = gridDim.x * HIST_THREADS;
    const int tid = blockIdx.x * HIST_THREADS + threadIdx.x;

    if (n4 == total_threads * PAIRS && (n & 3) == 0) {
        // Exact-cover straight-line path (n = 16.7M). All 16 loads issued in
        // ONE asm block. R4 CRASH ROOT-CAUSE: outputs were "=v" (no early
        // clobber), so LLVM aliased load destinations onto offset/base input
        // registers still read by LATER instructions in the block -> garbage
        // addresses -> memory fault. Every output is now "=&v" (early-clobber):
        // outputs and inputs provably disjoint, ~88 live VGPRs = the schedule.
        // Consumes drain behind counted vmcnt (14,12,...,0): the DS-atomic
        // pipe is fed continuously while remaining loads are still in flight.
        const int base = blockIdx.x * (HIST_THREADS * PAIRS) + threadIdx.x;
        const unsigned st = HIST_THREADS * 16u;          // 8 KB between k's
        const unsigned o0 = (unsigned)base * 16u;
        const unsigned o1 = o0 + st,     o2 = o0 + 2 * st, o3 = o0 + 3 * st,
                       o4 = o0 + 4 * st, o5 = o0 + 5 * st, o6 = o0 + 6 * st,
                       o7 = o0 + 7 * st;

        intx4 P0, P1, P2, P3, P4, P5, P6, P7;
        intx4 C0, C1, C2, C3, C4, C5, C6, C7;
        asm volatile(
            "global_load_dwordx4 %[P0], %[o0], %[pb]\n\t"
            "global_load_dwordx4 %[C0], %[o0], %[cb]\n\t"
            "global_load_dwordx4 %[P1], %[o1], %[pb]\n\t"
            "global_load_dwordx4 %[C1], %[o1], %[cb]\n\t"
            "global_load_dwordx4 %[P2], %[o2], %[pb]\n\t"
            "global_load_dwordx4 %[C2], %[o2], %[cb]\n\t"
            "global_load_dwordx4 %[P3], %[o3], %[pb]\n\t"
            "global_load_dwordx4 %[C3], %[o3], %[cb]\n\t"
            "global_load_dwordx4 %[P4], %[o4], %[pb]\n\t"
            "global_load_dwordx4 %[C4], %[o4], %[cb]\n\t"
            "global_load_dwordx4 %[P5], %[o5], %[pb]\n\t"
            "global_load_dwordx4 %[C5], %[o5], %[cb]\n\t"
            "global_load_dwordx4 %[P6], %[o6], %[pb]\n\t"
            "global_load_dwordx4 %[C6], %[o6], %[cb]\n\t"
            "global_load_dwordx4 %[P7], %[o7], %[pb]\n\t"
            "global_load_dwordx4 %[C7], %[o7], %[cb]"
            : [P0] "=&v"(P0), [C0] "=&v"(C0), [P1] "=&v"(P1), [C1] "=&v"(C1),
              [P2] "=&v"(P2), [C2] "=&v"(C2), [P3] "=&v"(P3), [C3] "=&v"(C3),
              [P4] "=&v"(P4), [C4] "=&v"(C4), [P5] "=&v"(P5), [C5] "=&v"(C5),
              [P6] "=&v"(P6), [C6] "=&v"(C6), [P7] "=&v"(P7), [C7] "=&v"(C7)
            : [o0] "v"(o0), [o1] "v"(o1), [o2] "v"(o2), [o3] "v"(o3),
              [o4] "v"(o4), [o5] "v"(o5), [o6] "v"(o6), [o7] "v"(o7),
              [pb] "s"(prev), [cb] "s"(curr)
            : "memory");

        WAITPAIR(14, P0, C0); CONS(P0, C0);
        WAITPAIR(12, P1, C1); CONS(P1, C1);
        WAITPAIR(10, P2, C2); CONS(P2, C2);
        WAITPAIR(8,  P3, C3); CONS(P3, C3);
        WAITPAIR(6,  P4, C4); CONS(P4, C4);
        WAITPAIR(4,  P5, C5); CONS(P5, C5);
        WAITPAIR(2,  P6, C6); CONS(P6, C6);
        WAITPAIR(0,  P7, C7); CONS(P7, C7);
    } else {
        // Generic fallback: grid-stride (correct for any n).
        const int4* __restrict__ p4 = (const int4*)prev;
        const int4* __restrict__ c4 = (const int4*)curr;
        for (int i = tid; i < n4; i += total_threads) {
            int4 p = p4[i];
            int4 c = c4[i];
            atomicAdd(&h[(p.x << 6) | c.x], 1u);
            atomicAdd(&h[(p.y << 6) | c.y], 1u);
            atomicAdd(&h[(p.z << 6) | c.z], 1u);
            atomicAdd(&h[(p.w << 6) | c.w], 1u);
        }
        for (int t = (n4 << 2) + tid; t < n; t += total_threads) {
            atomicAdd(&h[(prev[t] << 6) | curr[t]], 1u);
        }
    }

    __syncthreads();
    // R1 finding: this contended float-atomic flush is FREE (hist duration
    // identical with/without it) — keep the simple single-kernel form.
    for (int b = threadIdx.x; b < BINS; b += HIST_THREADS) {
        unsigned int c = h[b];
        if (c) atomicAdd(&out[b], (float)c);
    }
}

extern "C" void kernel_launch(void* const* d_in, const int* in_sizes, int n_in,
                              void* d_out, int out_size, void* d_ws, size_t ws_size,
                              hipStream_t stream) {
    const int*   prev        = (const int*)d_in[0];
    const int*   curr        = (const int*)d_in[1];
    const float* transitions = (const float*)d_in[2];
    const float* total       = (const float*)d_in[3];
    float* out = (float*)d_out;

    const int n    = in_sizes[0];
    const int bins = in_sizes[2];   // 4096

    // 1) initialize output: copy transitions input, set total = total_in + n
    int init_blocks = (bins + 1 + 255) / 256;
    topo_init_kernel<<<init_blocks, 256, 0, stream>>>(transitions, total, out,
                                                      (float)n, bins);

    // 2) per-block LDS histogram, asm-forced 16-deep load pipeline
    topo_hist_kernel<<<HIST_BLOCKS, HIST_THREADS, 0, stream>>>(prev, curr, out, n);
}